// Round 8
// baseline (396.135 us; speedup 1.0000x reference)
//
#include <hip/hip_runtime.h>
#include <stdint.h>

constexpr int B_ = 64, N_ = 2048, D_ = 256, H_ = 64;
constexpr int M_ = B_ * N_;           // 131072 rows
constexpr int TOPK_ = 204, TOP5_ = 102;
constexpr float NEGINF_ = -1e30f;

// out layout (floats)
constexpr int OUT_BAG  = 0;                      // 64*512
constexpr int OUT_ATTN = 32768;                  // 64*3*2048
constexpr int OUT_AVG  = OUT_ATTN + 393216;      // 425984
constexpr int OUT_TOPK = OUT_AVG + 131072;       // 557056
constexpr int OUT_ENT  = OUT_TOPK + 131072;      // 688128
constexpr int OUT_EFF  = OUT_ENT + 64;           // 688192
constexpr int OUT_T5   = OUT_EFF + 64;           // 688256

// ws layout (floats)
constexpr int WS_TK    = 0;                      // 131072
constexpr int WS_SC    = 131072;                 // [s*64+b][n] : 393216
constexpr int WS_STATS = WS_SC + 393216;         // 524288 : [b]=valid_sum, [64+b]=topk_sum
constexpr int WS_PART  = WS_STATS + 128;         // 524416 : [b*8+ch][5][256] = 655360
constexpr int WS_BFRAG = WS_PART + 655360;       // 1179776 : 131072 bf16 = 65536 floats

typedef short  bf16x8 __attribute__((ext_vector_type(8)));
typedef float  f32x4  __attribute__((ext_vector_type(4)));

__device__ __forceinline__ short cvt_bf16(float f) {
    unsigned u = __float_as_uint(f);
    unsigned r = (u + 0x7FFFu + ((u >> 16) & 1u)) >> 16;
    return (short)r;
}
// HW packed f32->bf16 (RNE), 2 elems/inst
__device__ __forceinline__ unsigned cvt_pk(float lo, float hi) {
    unsigned r;
    asm("v_cvt_pk_bf16_f32 %0, %1, %2" : "=v"(r) : "v"(lo), "v"(hi));
    return r;
}
__device__ __forceinline__ bf16x8 cvt8(float4 p, float4 q) {
    union { unsigned u[4]; bf16x8 v; } r;
    r.u[0] = cvt_pk(p.x, p.y);
    r.u[1] = cvt_pk(p.z, p.w);
    r.u[2] = cvt_pk(q.x, q.y);
    r.u[3] = cvt_pk(q.z, q.w);
    return r.v;
}
__device__ __forceinline__ float tanh_fast(float x) {
    float e = __expf(2.0f * x);
    return 1.0f - 2.0f / (e + 1.0f);
}
__device__ __forceinline__ unsigned flip_f32(float f) {
    unsigned u = __float_as_uint(f);
    return (u & 0x80000000u) ? ~u : (u | 0x80000000u);
}
__device__ __forceinline__ float unflip_f32(unsigned u) {
    unsigned b = (u & 0x80000000u) ? (u & 0x7FFFFFFFu) : ~u;
    return __uint_as_float(b);
}

__device__ __forceinline__ float block_sum256(float v, volatile float* red, int t) {
    #pragma unroll
    for (int off = 32; off; off >>= 1) v += __shfl_xor(v, off, 64);
    __syncthreads();
    if ((t & 63) == 0) red[t >> 6] = v;
    __syncthreads();
    return red[0] + red[1] + red[2] + red[3];
}
__device__ __forceinline__ float block_max256(float v, volatile float* red, int t) {
    #pragma unroll
    for (int off = 32; off; off >>= 1) v = fmaxf(v, __shfl_xor(v, off, 64));
    __syncthreads();
    if ((t & 63) == 0) red[t >> 6] = v;
    __syncthreads();
    return fmaxf(fmaxf(red[0], red[1]), fmaxf(red[2], red[3]));
}

// radix-select: exact key of the k-th largest among key[0..n) (flipped-float order).
// 4 wave-private 256-bin histograms; scan + digit-select by wave 0 via shuffles.
__device__ unsigned radix_kth(const unsigned* key, int n, int k,
                              unsigned* hist4, int* sdig, int t, int* rem_out)
{
    const int l = t & 63;
    unsigned prefix = 0;
    int kk = k;
    #pragma unroll
    for (int pass = 0; pass < 4; ++pass) {
        const int shift = 24 - 8 * pass;
        const unsigned hi_mask = (pass == 0) ? 0u : (0xFFFFFFFFu << (shift + 8));
        #pragma unroll
        for (int i = 0; i < 4; ++i) hist4[t + 256 * i] = 0;
        __syncthreads();
        const unsigned pfx = prefix & hi_mask;
        unsigned* myh = hist4 + ((t >> 6) << 8);     // wave-private copy
        for (int i = t; i < n; i += 256) {
            unsigned u = key[i];
            if ((u & hi_mask) == pfx)
                atomicAdd(&myh[(u >> shift) & 0xFFu], 1u);
        }
        __syncthreads();
        if (t < 64) {
            const int b0 = l << 2;
            unsigned c0 = hist4[b0]     + hist4[b0+256]   + hist4[b0+512]   + hist4[b0+768];
            unsigned c1 = hist4[b0+1]   + hist4[b0+257]   + hist4[b0+513]   + hist4[b0+769];
            unsigned c2 = hist4[b0+2]   + hist4[b0+258]   + hist4[b0+514]   + hist4[b0+770];
            unsigned c3 = hist4[b0+3]   + hist4[b0+259]   + hist4[b0+515]   + hist4[b0+771];
            unsigned S = c0 + c1 + c2 + c3;
            #pragma unroll
            for (int off = 1; off < 64; off <<= 1) {
                unsigned v = __shfl_down(S, off, 64);
                if (l + off < 64) S += v;
            }
            unsigned Sn = __shfl_down(S, 1, 64);
            if (l == 63) Sn = 0;
            unsigned s3 = c3 + Sn, s2 = c2 + s3, s1 = c1 + s2, s0 = c0 + s1;
            hist4[b0] = s0; hist4[b0+1] = s1; hist4[b0+2] = s2; hist4[b0+3] = s3;
            int cand = ((int)s3 >= kk) ? b0 + 3 :
                       ((int)s2 >= kk) ? b0 + 2 :
                       ((int)s1 >= kk) ? b0 + 1 :
                       ((int)s0 >= kk) ? b0     : -1;
            #pragma unroll
            for (int off = 1; off < 64; off <<= 1)
                cand = max(cand, __shfl_xor(cand, off, 64));
            if (l == 0) *sdig = cand;
        }
        __syncthreads();
        const int dig = *sdig;
        if (dig < 255) kk -= (int)hist4[dig + 1];
        prefix |= (unsigned)dig << shift;
        __syncthreads();
    }
    *rem_out = kk;
    return prefix;
}

// ---------------- K0: pack W = [Ws1 | Wa1_0 | Wa1_1 | Wa1_2] into bf16 B-fragments ----
__global__ __launch_bounds__(256)
void k_prep(const float* __restrict__ Ws1, const float* __restrict__ Wa1,
            short* __restrict__ wsB)
{
    const int id = blockIdx.x * 256 + threadIdx.x;   // 0..8191 : (c,ct,lane)
    if (id >= 8192) return;
    const int lane = id & 63, ct = (id >> 6) & 15, c = id >> 10;   // c in [0,8)
    const int col = ct * 16 + (lane & 15);
    const int kb  = c * 32 + ((lane >> 4) << 3);     // k in [0,256)
    bf16x8 v;
    #pragma unroll
    for (int j = 0; j < 8; ++j) {
        const int k = kb + j;
        float w = (col < 64) ? Ws1[(size_t)k * H_ + col]
                             : Wa1[(((size_t)(col >> 6) - 1) * D_ + k) * H_ + (col & 63)];
        v[j] = cvt_bf16(w);
    }
    *(bf16x8*)(wsB + (size_t)id * 8) = v;
}

// ---------------- K1: MFMA scorer + 3 attention-branch GEMM ----------------
// 64 rows/block, grid 2048. B-chunk (16 KB) double-buffered in LDS, staged by
// global_load_lds (width 16) one chunk ahead of compute; ONE barrier per chunk
// (none after the last). ~105 VGPR live -> 4 waves/SIMD; 32 KB LDS ->
// 4 blocks/CU resident = 16 waves/CU. bias/w2v loads deferred to epilogue.
__global__ __launch_bounds__(256, 4)
void k_scores(const float* __restrict__ inst, const float* __restrict__ mask,
              const short* __restrict__ wsB,
              const float* __restrict__ bs1, const float* __restrict__ Ws2,
              const float* __restrict__ bs2,
              const float* __restrict__ ba1, const float* __restrict__ Wa2,
              const float* __restrict__ ba2,
              float* __restrict__ ws)
{
    __shared__ __align__(16) short lbs[2][8192];     // 2 x 16 KB B-chunk dbuf
    const int t = threadIdx.x;
    const int w = t >> 6, l = t & 63;
    const int rg = l >> 4, li = l & 15;
    const int row0 = blockIdx.x * 64;
    const int myrow = row0 + w * 16 + li;
    const float* xrow = inst + (size_t)myrow * D_;

    // stage chunk 0 into buf 0: each wave stages its 4 KB quarter, lane-linear.
    // LDS dest is wave-uniform (w,i only); global src carries the lane offset.
    #pragma unroll
    for (int i = 0; i < 4; ++i) {
        __builtin_amdgcn_global_load_lds(
            (const __attribute__((address_space(1))) void*)(wsB + (w * 2048 + i * 512 + l * 8)),
            (__attribute__((address_space(3))) void*)(&lbs[0][w * 2048 + i * 512]),
            16, 0, 0);
    }
    float4 x0 = *(const float4*)(xrow + rg * 8);
    float4 x1 = *(const float4*)(xrow + rg * 8 + 4);

    f32x4 acc[16];
    #pragma unroll
    for (int ct = 0; ct < 16; ++ct) acc[ct] = (f32x4){0.f, 0.f, 0.f, 0.f};

    __syncthreads();

    for (int c = 0; c < 8; ++c) {
        if (c < 7) {                                 // stage next chunk, other buf
            const short* gs = wsB + (size_t)(c + 1) * 8192;
            short* ld = lbs[(c + 1) & 1];
            #pragma unroll
            for (int i = 0; i < 4; ++i) {
                __builtin_amdgcn_global_load_lds(
                    (const __attribute__((address_space(1))) void*)(gs + (w * 2048 + i * 512 + l * 8)),
                    (__attribute__((address_space(3))) void*)(ld + (w * 2048 + i * 512)),
                    16, 0, 0);
            }
        }
        bf16x8 a = cvt8(x0, x1);
        if (c < 7) {                                 // prefetch next x
            x0 = *(const float4*)(xrow + (c + 1) * 32 + rg * 8);
            x1 = *(const float4*)(xrow + (c + 1) * 32 + rg * 8 + 4);
        }
        const bf16x8* bl = (const bf16x8*)lbs[c & 1];
        #pragma unroll
        for (int ct = 0; ct < 16; ++ct) {
            bf16x8 bfrag = bl[ct * 64 + l];
            acc[ct] = __builtin_amdgcn_mfma_f32_16x16x32_bf16(a, bfrag, acc[ct], 0, 0, 0);
        }
        if (c < 7) __syncthreads();                  // stage(c+1) done; buf swap safe
    }

    // epilogue: score[row] = sum_h act(C+bias)*w2 ; bias/w2 loaded here (reg relief)
    const float bs2_v = bs2[0];
    float ba2_v[3] = {ba2[0], ba2[1], ba2[2]};
    #pragma unroll
    for (int s = 0; s < 4; ++s) {
        float bias[4], w2v[4];
        #pragma unroll
        for (int q = 0; q < 4; ++q) {
            const int col = (s * 4 + q) * 16 + li;
            const int ss = col >> 6, h = col & 63;
            if (ss == 0) { bias[q] = bs1[h];                w2v[q] = Ws2[h]; }
            else         { bias[q] = ba1[(ss - 1) * H_ + h]; w2v[q] = Wa2[(ss - 1) * H_ + h]; }
        }
        float res[4];
        #pragma unroll
        for (int i = 0; i < 4; ++i) {
            float p = 0.0f;
            #pragma unroll
            for (int q = 0; q < 4; ++q) {
                float v = acc[s * 4 + q][i] + bias[q];
                p += (s == 0 ? fmaxf(v, 0.0f) : tanh_fast(v)) * w2v[q];
            }
            #pragma unroll
            for (int off = 1; off < 16; off <<= 1) p += __shfl_xor(p, off, 64);
            res[i] = p;
        }
        if (li == 0) {
            #pragma unroll
            for (int i = 0; i < 4; ++i) {
                const int gr = row0 + w * 16 + rg * 4 + i;
                const bool inv = (mask[gr] == 0.0f);
                float val = res[i] + (s == 0 ? bs2_v : ba2_v[s - 1]);
                float* dst = (s == 0) ? (ws + WS_TK + gr)
                                      : (ws + WS_SC + (size_t)(s - 1) * M_ + gr);
                *dst = inv ? NEGINF_ : val;
            }
        }
    }
}

// ---------------- K2: merged top-204 select (blocks 0..63) + softmax (64..255) ----
__global__ __launch_bounds__(256)
void k_sel(const float* __restrict__ ws_tk, const float* __restrict__ ws_sc,
           const float* __restrict__ mask,
           float* __restrict__ out_topk, float* __restrict__ out_attn,
           float* __restrict__ ws_stats)
{
    __shared__ __align__(16) char smem[12352];
    const int t = threadIdx.x;
    if (blockIdx.x < 64) {
        unsigned* ukey  = (unsigned*)smem;            // 8 KB
        unsigned* hist4 = (unsigned*)(smem + 8192);   // 4 KB
        int*   sdig    = (int*)(smem + 12288);
        int*   tie_cnt = (int*)(smem + 12292);
        float* red     = (float*)(smem + 12304);      // 16 B
        const int b = blockIdx.x;
        float vsum = 0.0f;
        for (int i = t; i < N_; i += 256) {
            ukey[i] = flip_f32(ws_tk[b * N_ + i]);
            vsum += mask[b * N_ + i];
            out_topk[b * N_ + i] = 0.0f;
        }
        float vs = block_sum256(vsum, red, t);
        if (t == 0) { ws_stats[b] = vs; *tie_cnt = 0; }
        __syncthreads();
        int rem;
        const unsigned T = radix_kth(ukey, N_, TOPK_, hist4, sdig, t, &rem);
        float csum = 0.0f;
        for (int i = t; i < N_; i += 256) {
            const unsigned u = ukey[i];
            bool take = (u > T);
            if (!take && u == T) take = (atomicAdd(tie_cnt, 1) < rem);
            if (take) {
                out_topk[b * N_ + i] = 1.0f;
                csum += mask[b * N_ + i];
            }
        }
        float cs = block_sum256(csum, red, t);
        if (t == 0) ws_stats[64 + b] = cs;
    } else {
        float* red = (float*)smem;
        const int sb = blockIdx.x - 64;               // s*64 + b
        const int s = sb >> 6, b = sb & 63;
        const float* src = ws_sc + (size_t)sb * N_;
        float fv[8];
        float mx = -3.4e38f;
        #pragma unroll
        for (int m = 0; m < 8; ++m) { fv[m] = src[t + 256 * m]; mx = fmaxf(mx, fv[m]); }
        float bm = block_max256(mx, red, t);
        float sm = 0.0f;
        #pragma unroll
        for (int m = 0; m < 8; ++m) { fv[m] = expf(fv[m] - bm); sm += fv[m]; }
        float tot = block_sum256(sm, red, t);
        float inv = 1.0f / tot;
        float* dst = out_attn + ((size_t)b * 3 + s) * N_;
        #pragma unroll
        for (int m = 0; m < 8; ++m) dst[t + 256 * m] = fv[m] * inv;
    }
}

// ---------------- K3: merged pooling partials (blocks 0..511) + diagnostics (512..575) ----
__global__ __launch_bounds__(256)
void k_pd(const float* __restrict__ inst, const float* __restrict__ mask,
          const float* __restrict__ out_topk, const float* __restrict__ out_attn,
          float* __restrict__ ws_part,
          float* __restrict__ out_avg, float* __restrict__ out_ent,
          float* __restrict__ out_eff, float* __restrict__ out_t5)
{
    __shared__ __align__(16) char smem[25600];
    const int t = threadIdx.x;
    if (blockIdx.x < 512) {
        float (*wgt)[256] = (float(*)[256])smem;                  // 5 KB
        float4 (*partial)[5][64] = (float4(*)[5][64])(smem + 5120); // 20 KB
        const int blk = blockIdx.x;                 // b*8 + ch
        const int b = blk >> 3, ch = blk & 7;
        const int n0 = ch * 256;
        const int w = t >> 6, l = t & 63;
        {
            float mv = mask[b * N_ + n0 + t];
            wgt[0][t] = mv;
            wgt[1][t] = out_topk[b * N_ + n0 + t] * mv;
            const float* ab = out_attn + (size_t)b * 3 * N_ + n0 + t;
            wgt[2][t] = ab[0];
            wgt[3][t] = ab[N_];
            wgt[4][t] = ab[2 * N_];
        }
        __syncthreads();
        float4 a0 = {0,0,0,0}, a1 = {0,0,0,0}, a2 = {0,0,0,0}, a3 = {0,0,0,0}, a4 = {0,0,0,0};
        const float4* xp = (const float4*)(inst + ((size_t)b * N_ + n0 + w * 64) * D_) + l;
        #pragma unroll 8
        for (int nn = 0; nn < 64; ++nn) {
            float4 x = xp[(size_t)nn * 64];
            float w0 = wgt[0][w * 64 + nn], w1 = wgt[1][w * 64 + nn];
            float w2 = wgt[2][w * 64 + nn], w3 = wgt[3][w * 64 + nn];
            float w4 = wgt[4][w * 64 + nn];
            a0.x = fmaf(x.x, w0, a0.x); a0.y = fmaf(x.y, w0, a0.y);
            a0.z = fmaf(x.z, w0, a0.z); a0.w = fmaf(x.w, w0, a0.w);
            a1.x = fmaf(x.x, w1, a1.x); a1.y = fmaf(x.y, w1, a1.y);
            a1.z = fmaf(x.z, w1, a1.z); a1.w = fmaf(x.w, w1, a1.w);
            a2.x = fmaf(x.x, w2, a2.x); a2.y = fmaf(x.y, w2, a2.y);
            a2.z = fmaf(x.z, w2, a2.z); a2.w = fmaf(x.w, w2, a2.w);
            a3.x = fmaf(x.x, w3, a3.x); a3.y = fmaf(x.y, w3, a3.y);
            a3.z = fmaf(x.z, w3, a3.z); a3.w = fmaf(x.w, w3, a3.w);
            a4.x = fmaf(x.x, w4, a4.x); a4.y = fmaf(x.y, w4, a4.y);
            a4.z = fmaf(x.z, w4, a4.z); a4.w = fmaf(x.w, w4, a4.w);
        }
        partial[w][0][l] = a0; partial[w][1][l] = a1; partial[w][2][l] = a2;
        partial[w][3][l] = a3; partial[w][4][l] = a4;
        __syncthreads();
        for (int idx = t; idx < 320; idx += 256) {
            const int j = idx >> 6, l2 = idx & 63;
            float4 s0 = partial[0][j][l2], s1 = partial[1][j][l2];
            float4 s2 = partial[2][j][l2], s3 = partial[3][j][l2];
            float4 sm;
            sm.x = s0.x + s1.x + s2.x + s3.x;
            sm.y = s0.y + s1.y + s2.y + s3.y;
            sm.z = s0.z + s1.z + s2.z + s3.z;
            sm.w = s0.w + s1.w + s2.w + s3.w;
            *(float4*)(ws_part + (size_t)blk * 1280 + j * 256 + l2 * 4) = sm;
        }
    } else {
        unsigned* ukey  = (unsigned*)smem;            // 8 KB
        unsigned* hist4 = (unsigned*)(smem + 8192);   // 4 KB
        int*   sdig = (int*)(smem + 12288);
        float* red  = (float*)(smem + 12304);
        const int b = blockIdx.x - 512;
        const float* a0 = out_attn + (size_t)b * 3 * N_;
        float esum = 0.0f, qsum = 0.0f;
        for (int i = t; i < N_; i += 256) {
            float a = (a0[i] + a0[N_ + i] + a0[2 * N_ + i]) * (1.0f / 3.0f);
            out_avg[b * N_ + i] = a;
            esum -= a * logf(a + 1e-8f);
            qsum += a * a;
            ukey[i] = flip_f32(a);
        }
        float es = block_sum256(esum, red, t);
        float qs = block_sum256(qsum, red, t);
        if (t == 0) { out_ent[b] = es; out_eff[b] = 1.0f / qs; }
        __syncthreads();
        int rem;
        const unsigned T = radix_kth(ukey, N_, TOP5_, hist4, sdig, t, &rem);
        float tsum = 0.0f;
        for (int i = t; i < N_; i += 256) {
            const unsigned u = ukey[i];
            if (u > T) tsum += unflip_f32(u);
        }
        float ts = block_sum256(tsum, red, t);
        if (t == 0) out_t5[b] = ts + (float)rem * unflip_f32(T);
    }
}

// ---------------- K4: fused MLP — x1 = cat@Wf1+bf1 ; LN ; GELU ; bag = g@Wf2+bf2 ----
// One block per batch. Each thread owns output cols t and t+256 end-to-end; the
// concat vector and GELU output live in LDS; no intermediate global round-trips.
__global__ __launch_bounds__(256)
void k_fuse(const float* __restrict__ ws_part, const float* __restrict__ ws_stats,
            const float* __restrict__ Wf1, const float* __restrict__ bf1,
            const float* __restrict__ ln_g, const float* __restrict__ ln_b,
            const float* __restrict__ Wf2, const float* __restrict__ bf2,
            float* __restrict__ out_bag)
{
    __shared__ float cl[1280];
    __shared__ float gl[512];
    __shared__ float red[4];
    const int b = blockIdx.x, t = threadIdx.x;
    const float inv0 = 1.0f / fmaxf(ws_stats[b], 1.0f);
    const float inv1 = 1.0f / fmaxf(ws_stats[64 + b], 1.0f);
    for (int i = t; i < 1280; i += 256) {
        const int j = i >> 8, d = i & 255;
        float s = 0.0f;
        #pragma unroll
        for (int cc = 0; cc < 8; ++cc)
            s += ws_part[((size_t)(b * 8 + cc) * 5 + j) * 256 + d];
        if (j == 0)      s *= inv0;
        else if (j == 1) s *= inv1;
        cl[i] = s;
    }
    __syncthreads();

    float a0 = 0.0f, a1 = 0.0f;
    const float* wp = Wf1 + t;
    #pragma unroll 8
    for (int i = 0; i < 1280; ++i) {
        float c = cl[i];
        a0 = fmaf(c, wp[(size_t)i * 512], a0);
        a1 = fmaf(c, wp[(size_t)i * 512 + 256], a1);
    }
    float v0 = a0 + bf1[t], v1 = a1 + bf1[t + 256];

    float mu = block_sum256(v0 + v1, red, t) * (1.0f / 512.0f);
    float d0 = v0 - mu, d1 = v1 - mu;
    float var = block_sum256(d0 * d0 + d1 * d1, red, t) * (1.0f / 512.0f);
    float is = 1.0f / sqrtf(var + 1e-5f);
    float y0 = d0 * is * ln_g[t] + ln_b[t];
    float y1 = d1 * is * ln_g[t + 256] + ln_b[t + 256];
    gl[t]       = 0.5f * y0 * (1.0f + erff(y0 * 0.70710678118654752440f));
    gl[t + 256] = 0.5f * y1 * (1.0f + erff(y1 * 0.70710678118654752440f));
    __syncthreads();

    float b0 = 0.0f, b1 = 0.0f;
    const float* wq = Wf2 + t;
    #pragma unroll 8
    for (int i = 0; i < 512; ++i) {
        float g = gl[i];
        b0 = fmaf(g, wq[(size_t)i * 512], b0);
        b1 = fmaf(g, wq[(size_t)i * 512 + 256], b1);
    }
    out_bag[b * 512 + t]       = b0 + bf2[t];
    out_bag[b * 512 + 256 + t] = b1 + bf2[t + 256];
}

extern "C" void kernel_launch(void* const* d_in, const int* in_sizes, int n_in,
                              void* d_out, int out_size, void* d_ws, size_t ws_size,
                              hipStream_t stream)
{
    (void)in_sizes; (void)n_in; (void)out_size; (void)ws_size;
    const float* inst = (const float*)d_in[0];
    const float* mask = (const float*)d_in[1];
    const float* Ws1  = (const float*)d_in[2];
    const float* bs1  = (const float*)d_in[3];
    const float* Ws2  = (const float*)d_in[4];
    const float* bs2  = (const float*)d_in[5];
    const float* Wa1  = (const float*)d_in[6];
    const float* ba1  = (const float*)d_in[7];
    const float* Wa2  = (const float*)d_in[8];
    const float* ba2  = (const float*)d_in[9];
    const float* Wf1  = (const float*)d_in[10];
    const float* bf1  = (const float*)d_in[11];
    const float* lng  = (const float*)d_in[12];
    const float* lnb  = (const float*)d_in[13];
    const float* Wf2  = (const float*)d_in[14];
    const float* bf2  = (const float*)d_in[15];

    float* out = (float*)d_out;
    float* ws  = (float*)d_ws;
    short* wsB = (short*)(ws + WS_BFRAG);

    k_prep<<<32, 256, 0, stream>>>(Ws1, Wa1, wsB);
    k_scores<<<M_ / 64, 256, 0, stream>>>(inst, mask, wsB, bs1, Ws2, bs2,
                                          ba1, Wa2, ba2, ws);
    k_sel<<<256, 256, 0, stream>>>(ws + WS_TK, ws + WS_SC, mask,
                                   out + OUT_TOPK, out + OUT_ATTN, ws + WS_STATS);
    k_pd<<<576, 256, 0, stream>>>(inst, mask, out + OUT_TOPK, out + OUT_ATTN,
                                  ws + WS_PART, out + OUT_AVG, out + OUT_ENT,
                                  out + OUT_EFF, out + OUT_T5);
    k_fuse<<<B_, 256, 0, stream>>>(ws + WS_PART, ws + WS_STATS, Wf1, bf1,
                                   lng, lnb, Wf2, bf2, out + OUT_BAG);
}

// Round 9
// 309.795 us; speedup vs baseline: 1.2787x; 1.2787x over previous
//
#include <hip/hip_runtime.h>
#include <stdint.h>

constexpr int B_ = 64, N_ = 2048, D_ = 256, H_ = 64;
constexpr int M_ = B_ * N_;           // 131072 rows
constexpr int TOPK_ = 204, TOP5_ = 102;
constexpr float NEGINF_ = -1e30f;

// out layout (floats)
constexpr int OUT_BAG  = 0;                      // 64*512
constexpr int OUT_ATTN = 32768;                  // 64*3*2048
constexpr int OUT_AVG  = OUT_ATTN + 393216;      // 425984
constexpr int OUT_TOPK = OUT_AVG + 131072;       // 557056
constexpr int OUT_ENT  = OUT_TOPK + 131072;      // 688128
constexpr int OUT_EFF  = OUT_ENT + 64;           // 688192
constexpr int OUT_T5   = OUT_EFF + 64;           // 688256

// ws layout (floats)
constexpr int WS_TK    = 0;                      // 131072
constexpr int WS_SC    = 131072;                 // [s*64+b][n] : 393216
constexpr int WS_STATS = WS_SC + 393216;         // 524288 : [b]=valid_sum, [64+b]=topk_sum
constexpr int WS_PART  = WS_STATS + 128;         // 524416 : [b*8+ch][5][256] = 655360
constexpr int WS_BFRAG = WS_PART + 655360;       // 1179776 : 131072 bf16 = 65536 floats
constexpr int WS_X1    = WS_BFRAG + 32768;       // 1212544 : [b][512]

typedef short  bf16x8 __attribute__((ext_vector_type(8)));
typedef float  f32x4  __attribute__((ext_vector_type(4)));

__device__ __forceinline__ short cvt_bf16(float f) {
    unsigned u = __float_as_uint(f);
    unsigned r = (u + 0x7FFFu + ((u >> 16) & 1u)) >> 16;
    return (short)r;
}
// HW packed f32->bf16 (RNE), 2 elems/inst
__device__ __forceinline__ unsigned cvt_pk(float lo, float hi) {
    unsigned r;
    asm("v_cvt_pk_bf16_f32 %0, %1, %2" : "=v"(r) : "v"(lo), "v"(hi));
    return r;
}
__device__ __forceinline__ bf16x8 cvt8(float4 p, float4 q) {
    union { unsigned u[4]; bf16x8 v; } r;
    r.u[0] = cvt_pk(p.x, p.y);
    r.u[1] = cvt_pk(p.z, p.w);
    r.u[2] = cvt_pk(q.x, q.y);
    r.u[3] = cvt_pk(q.z, q.w);
    return r.v;
}
__device__ __forceinline__ float tanh_fast(float x) {
    float e = __expf(2.0f * x);
    return 1.0f - 2.0f / (e + 1.0f);
}
__device__ __forceinline__ unsigned flip_f32(float f) {
    unsigned u = __float_as_uint(f);
    return (u & 0x80000000u) ? ~u : (u | 0x80000000u);
}
__device__ __forceinline__ float unflip_f32(unsigned u) {
    unsigned b = (u & 0x80000000u) ? (u & 0x7FFFFFFFu) : ~u;
    return __uint_as_float(b);
}

__device__ __forceinline__ float block_sum256(float v, volatile float* red, int t) {
    #pragma unroll
    for (int off = 32; off; off >>= 1) v += __shfl_xor(v, off, 64);
    __syncthreads();
    if ((t & 63) == 0) red[t >> 6] = v;
    __syncthreads();
    return red[0] + red[1] + red[2] + red[3];
}
__device__ __forceinline__ float block_max256(float v, volatile float* red, int t) {
    #pragma unroll
    for (int off = 32; off; off >>= 1) v = fmaxf(v, __shfl_xor(v, off, 64));
    __syncthreads();
    if ((t & 63) == 0) red[t >> 6] = v;
    __syncthreads();
    return fmaxf(fmaxf(red[0], red[1]), fmaxf(red[2], red[3]));
}

// radix-select: exact key of the k-th largest among key[0..n) (flipped-float order).
// 4 wave-private 256-bin histograms; scan + digit-select by wave 0 via shuffles.
__device__ unsigned radix_kth(const unsigned* key, int n, int k,
                              unsigned* hist4, int* sdig, int t, int* rem_out)
{
    const int l = t & 63;
    unsigned prefix = 0;
    int kk = k;
    #pragma unroll
    for (int pass = 0; pass < 4; ++pass) {
        const int shift = 24 - 8 * pass;
        const unsigned hi_mask = (pass == 0) ? 0u : (0xFFFFFFFFu << (shift + 8));
        #pragma unroll
        for (int i = 0; i < 4; ++i) hist4[t + 256 * i] = 0;
        __syncthreads();
        const unsigned pfx = prefix & hi_mask;
        unsigned* myh = hist4 + ((t >> 6) << 8);     // wave-private copy
        for (int i = t; i < n; i += 256) {
            unsigned u = key[i];
            if ((u & hi_mask) == pfx)
                atomicAdd(&myh[(u >> shift) & 0xFFu], 1u);
        }
        __syncthreads();
        if (t < 64) {
            const int b0 = l << 2;
            unsigned c0 = hist4[b0]     + hist4[b0+256]   + hist4[b0+512]   + hist4[b0+768];
            unsigned c1 = hist4[b0+1]   + hist4[b0+257]   + hist4[b0+513]   + hist4[b0+769];
            unsigned c2 = hist4[b0+2]   + hist4[b0+258]   + hist4[b0+514]   + hist4[b0+770];
            unsigned c3 = hist4[b0+3]   + hist4[b0+259]   + hist4[b0+515]   + hist4[b0+771];
            unsigned S = c0 + c1 + c2 + c3;
            #pragma unroll
            for (int off = 1; off < 64; off <<= 1) {
                unsigned v = __shfl_down(S, off, 64);
                if (l + off < 64) S += v;
            }
            unsigned Sn = __shfl_down(S, 1, 64);
            if (l == 63) Sn = 0;
            unsigned s3 = c3 + Sn, s2 = c2 + s3, s1 = c1 + s2, s0 = c0 + s1;
            hist4[b0] = s0; hist4[b0+1] = s1; hist4[b0+2] = s2; hist4[b0+3] = s3;
            int cand = ((int)s3 >= kk) ? b0 + 3 :
                       ((int)s2 >= kk) ? b0 + 2 :
                       ((int)s1 >= kk) ? b0 + 1 :
                       ((int)s0 >= kk) ? b0     : -1;
            #pragma unroll
            for (int off = 1; off < 64; off <<= 1)
                cand = max(cand, __shfl_xor(cand, off, 64));
            if (l == 0) *sdig = cand;
        }
        __syncthreads();
        const int dig = *sdig;
        if (dig < 255) kk -= (int)hist4[dig + 1];
        prefix |= (unsigned)dig << shift;
        __syncthreads();
    }
    *rem_out = kk;
    return prefix;
}

// ---------------- K0: pack W = [Ws1 | Wa1_0 | Wa1_1 | Wa1_2] into bf16 B-fragments ----
__global__ __launch_bounds__(256)
void k_prep(const float* __restrict__ Ws1, const float* __restrict__ Wa1,
            short* __restrict__ wsB)
{
    const int id = blockIdx.x * 256 + threadIdx.x;   // 0..8191 : (c,ct,lane)
    if (id >= 8192) return;
    const int lane = id & 63, ct = (id >> 6) & 15, c = id >> 10;   // c in [0,8)
    const int col = ct * 16 + (lane & 15);
    const int kb  = c * 32 + ((lane >> 4) << 3);     // k in [0,256)
    bf16x8 v;
    #pragma unroll
    for (int j = 0; j < 8; ++j) {
        const int k = kb + j;
        float w = (col < 64) ? Ws1[(size_t)k * H_ + col]
                             : Wa1[(((size_t)(col >> 6) - 1) * D_ + k) * H_ + (col & 63)];
        v[j] = cvt_bf16(w);
    }
    *(bf16x8*)(wsB + (size_t)id * 8) = v;
}

// ---------------- K1: MFMA scorer + 3 attention-branch GEMM ----------------
// 64 rows/block, grid 2048. B-chunk (16 KB) double-buffered in LDS, staged by
// global_load_lds (width 16) one chunk ahead of compute; ONE barrier per chunk
// (none after the last). ~105 VGPR live -> 4 waves/SIMD; 32 KB LDS ->
// 4 blocks/CU resident = 16 waves/CU. bias/w2v loads deferred to epilogue.
__global__ __launch_bounds__(256, 4)
void k_scores(const float* __restrict__ inst, const float* __restrict__ mask,
              const short* __restrict__ wsB,
              const float* __restrict__ bs1, const float* __restrict__ Ws2,
              const float* __restrict__ bs2,
              const float* __restrict__ ba1, const float* __restrict__ Wa2,
              const float* __restrict__ ba2,
              float* __restrict__ ws)
{
    __shared__ __align__(16) short lbs[2][8192];     // 2 x 16 KB B-chunk dbuf
    const int t = threadIdx.x;
    const int w = t >> 6, l = t & 63;
    const int rg = l >> 4, li = l & 15;
    const int row0 = blockIdx.x * 64;
    const int myrow = row0 + w * 16 + li;
    const float* xrow = inst + (size_t)myrow * D_;

    // stage chunk 0 into buf 0: each wave stages its 4 KB quarter, lane-linear.
    // LDS dest is wave-uniform (w,i only); global src carries the lane offset.
    #pragma unroll
    for (int i = 0; i < 4; ++i) {
        __builtin_amdgcn_global_load_lds(
            (const __attribute__((address_space(1))) void*)(wsB + (w * 2048 + i * 512 + l * 8)),
            (__attribute__((address_space(3))) void*)(&lbs[0][w * 2048 + i * 512]),
            16, 0, 0);
    }
    float4 x0 = *(const float4*)(xrow + rg * 8);
    float4 x1 = *(const float4*)(xrow + rg * 8 + 4);

    f32x4 acc[16];
    #pragma unroll
    for (int ct = 0; ct < 16; ++ct) acc[ct] = (f32x4){0.f, 0.f, 0.f, 0.f};

    __syncthreads();

    for (int c = 0; c < 8; ++c) {
        if (c < 7) {                                 // stage next chunk, other buf
            const short* gs = wsB + (size_t)(c + 1) * 8192;
            short* ld = lbs[(c + 1) & 1];
            #pragma unroll
            for (int i = 0; i < 4; ++i) {
                __builtin_amdgcn_global_load_lds(
                    (const __attribute__((address_space(1))) void*)(gs + (w * 2048 + i * 512 + l * 8)),
                    (__attribute__((address_space(3))) void*)(ld + (w * 2048 + i * 512)),
                    16, 0, 0);
            }
        }
        bf16x8 a = cvt8(x0, x1);
        if (c < 7) {                                 // prefetch next x
            x0 = *(const float4*)(xrow + (c + 1) * 32 + rg * 8);
            x1 = *(const float4*)(xrow + (c + 1) * 32 + rg * 8 + 4);
        }
        const bf16x8* bl = (const bf16x8*)lbs[c & 1];
        #pragma unroll
        for (int ct = 0; ct < 16; ++ct) {
            bf16x8 bfrag = bl[ct * 64 + l];
            acc[ct] = __builtin_amdgcn_mfma_f32_16x16x32_bf16(a, bfrag, acc[ct], 0, 0, 0);
        }
        if (c < 7) __syncthreads();                  // stage(c+1) done; buf swap safe
    }

    // epilogue: score[row] = sum_h act(C+bias)*w2 ; bias/w2 loaded here (reg relief)
    const float bs2_v = bs2[0];
    float ba2_v[3] = {ba2[0], ba2[1], ba2[2]};
    #pragma unroll
    for (int s = 0; s < 4; ++s) {
        float bias[4], w2v[4];
        #pragma unroll
        for (int q = 0; q < 4; ++q) {
            const int col = (s * 4 + q) * 16 + li;
            const int ss = col >> 6, h = col & 63;
            if (ss == 0) { bias[q] = bs1[h];                w2v[q] = Ws2[h]; }
            else         { bias[q] = ba1[(ss - 1) * H_ + h]; w2v[q] = Wa2[(ss - 1) * H_ + h]; }
        }
        float res[4];
        #pragma unroll
        for (int i = 0; i < 4; ++i) {
            float p = 0.0f;
            #pragma unroll
            for (int q = 0; q < 4; ++q) {
                float v = acc[s * 4 + q][i] + bias[q];
                p += (s == 0 ? fmaxf(v, 0.0f) : tanh_fast(v)) * w2v[q];
            }
            #pragma unroll
            for (int off = 1; off < 16; off <<= 1) p += __shfl_xor(p, off, 64);
            res[i] = p;
        }
        if (li == 0) {
            #pragma unroll
            for (int i = 0; i < 4; ++i) {
                const int gr = row0 + w * 16 + rg * 4 + i;
                const bool inv = (mask[gr] == 0.0f);
                float val = res[i] + (s == 0 ? bs2_v : ba2_v[s - 1]);
                float* dst = (s == 0) ? (ws + WS_TK + gr)
                                      : (ws + WS_SC + (size_t)(s - 1) * M_ + gr);
                *dst = inv ? NEGINF_ : val;
            }
        }
    }
}

// ---------------- K2: merged top-204 select (blocks 0..63) + softmax (64..255) ----
__global__ __launch_bounds__(256)
void k_sel(const float* __restrict__ ws_tk, const float* __restrict__ ws_sc,
           const float* __restrict__ mask,
           float* __restrict__ out_topk, float* __restrict__ out_attn,
           float* __restrict__ ws_stats)
{
    __shared__ __align__(16) char smem[12352];
    const int t = threadIdx.x;
    if (blockIdx.x < 64) {
        unsigned* ukey  = (unsigned*)smem;            // 8 KB
        unsigned* hist4 = (unsigned*)(smem + 8192);   // 4 KB
        int*   sdig    = (int*)(smem + 12288);
        int*   tie_cnt = (int*)(smem + 12292);
        float* red     = (float*)(smem + 12304);      // 16 B
        const int b = blockIdx.x;
        float vsum = 0.0f;
        for (int i = t; i < N_; i += 256) {
            ukey[i] = flip_f32(ws_tk[b * N_ + i]);
            vsum += mask[b * N_ + i];
            out_topk[b * N_ + i] = 0.0f;
        }
        float vs = block_sum256(vsum, red, t);
        if (t == 0) { ws_stats[b] = vs; *tie_cnt = 0; }
        __syncthreads();
        int rem;
        const unsigned T = radix_kth(ukey, N_, TOPK_, hist4, sdig, t, &rem);
        float csum = 0.0f;
        for (int i = t; i < N_; i += 256) {
            const unsigned u = ukey[i];
            bool take = (u > T);
            if (!take && u == T) take = (atomicAdd(tie_cnt, 1) < rem);
            if (take) {
                out_topk[b * N_ + i] = 1.0f;
                csum += mask[b * N_ + i];
            }
        }
        float cs = block_sum256(csum, red, t);
        if (t == 0) ws_stats[64 + b] = cs;
    } else {
        float* red = (float*)smem;
        const int sb = blockIdx.x - 64;               // s*64 + b
        const int s = sb >> 6, b = sb & 63;
        const float* src = ws_sc + (size_t)sb * N_;
        float fv[8];
        float mx = -3.4e38f;
        #pragma unroll
        for (int m = 0; m < 8; ++m) { fv[m] = src[t + 256 * m]; mx = fmaxf(mx, fv[m]); }
        float bm = block_max256(mx, red, t);
        float sm = 0.0f;
        #pragma unroll
        for (int m = 0; m < 8; ++m) { fv[m] = expf(fv[m] - bm); sm += fv[m]; }
        float tot = block_sum256(sm, red, t);
        float inv = 1.0f / tot;
        float* dst = out_attn + ((size_t)b * 3 + s) * N_;
        #pragma unroll
        for (int m = 0; m < 8; ++m) dst[t + 256 * m] = fv[m] * inv;
    }
}

// ---------------- K3: merged pooling partials (blocks 0..511) + diagnostics (512..575) ----
__global__ __launch_bounds__(256)
void k_pd(const float* __restrict__ inst, const float* __restrict__ mask,
          const float* __restrict__ out_topk, const float* __restrict__ out_attn,
          float* __restrict__ ws_part,
          float* __restrict__ out_avg, float* __restrict__ out_ent,
          float* __restrict__ out_eff, float* __restrict__ out_t5)
{
    __shared__ __align__(16) char smem[25600];
    const int t = threadIdx.x;
    if (blockIdx.x < 512) {
        float (*wgt)[256] = (float(*)[256])smem;                  // 5 KB
        float4 (*partial)[5][64] = (float4(*)[5][64])(smem + 5120); // 20 KB
        const int blk = blockIdx.x;                 // b*8 + ch
        const int b = blk >> 3, ch = blk & 7;
        const int n0 = ch * 256;
        const int w = t >> 6, l = t & 63;
        {
            float mv = mask[b * N_ + n0 + t];
            wgt[0][t] = mv;
            wgt[1][t] = out_topk[b * N_ + n0 + t] * mv;
            const float* ab = out_attn + (size_t)b * 3 * N_ + n0 + t;
            wgt[2][t] = ab[0];
            wgt[3][t] = ab[N_];
            wgt[4][t] = ab[2 * N_];
        }
        __syncthreads();
        float4 a0 = {0,0,0,0}, a1 = {0,0,0,0}, a2 = {0,0,0,0}, a3 = {0,0,0,0}, a4 = {0,0,0,0};
        const float4* xp = (const float4*)(inst + ((size_t)b * N_ + n0 + w * 64) * D_) + l;
        #pragma unroll 8
        for (int nn = 0; nn < 64; ++nn) {
            float4 x = xp[(size_t)nn * 64];
            float w0 = wgt[0][w * 64 + nn], w1 = wgt[1][w * 64 + nn];
            float w2 = wgt[2][w * 64 + nn], w3 = wgt[3][w * 64 + nn];
            float w4 = wgt[4][w * 64 + nn];
            a0.x = fmaf(x.x, w0, a0.x); a0.y = fmaf(x.y, w0, a0.y);
            a0.z = fmaf(x.z, w0, a0.z); a0.w = fmaf(x.w, w0, a0.w);
            a1.x = fmaf(x.x, w1, a1.x); a1.y = fmaf(x.y, w1, a1.y);
            a1.z = fmaf(x.z, w1, a1.z); a1.w = fmaf(x.w, w1, a1.w);
            a2.x = fmaf(x.x, w2, a2.x); a2.y = fmaf(x.y, w2, a2.y);
            a2.z = fmaf(x.z, w2, a2.z); a2.w = fmaf(x.w, w2, a2.w);
            a3.x = fmaf(x.x, w3, a3.x); a3.y = fmaf(x.y, w3, a3.y);
            a3.z = fmaf(x.z, w3, a3.z); a3.w = fmaf(x.w, w3, a3.w);
            a4.x = fmaf(x.x, w4, a4.x); a4.y = fmaf(x.y, w4, a4.y);
            a4.z = fmaf(x.z, w4, a4.z); a4.w = fmaf(x.w, w4, a4.w);
        }
        partial[w][0][l] = a0; partial[w][1][l] = a1; partial[w][2][l] = a2;
        partial[w][3][l] = a3; partial[w][4][l] = a4;
        __syncthreads();
        for (int idx = t; idx < 320; idx += 256) {
            const int j = idx >> 6, l2 = idx & 63;
            float4 s0 = partial[0][j][l2], s1 = partial[1][j][l2];
            float4 s2 = partial[2][j][l2], s3 = partial[3][j][l2];
            float4 sm;
            sm.x = s0.x + s1.x + s2.x + s3.x;
            sm.y = s0.y + s1.y + s2.y + s3.y;
            sm.z = s0.z + s1.z + s2.z + s3.z;
            sm.w = s0.w + s1.w + s2.w + s3.w;
            *(float4*)(ws_part + (size_t)blk * 1280 + j * 256 + l2 * 4) = sm;
        }
    } else {
        unsigned* ukey  = (unsigned*)smem;            // 8 KB
        unsigned* hist4 = (unsigned*)(smem + 8192);   // 4 KB
        int*   sdig = (int*)(smem + 12288);
        float* red  = (float*)(smem + 12304);
        const int b = blockIdx.x - 512;
        const float* a0 = out_attn + (size_t)b * 3 * N_;
        float esum = 0.0f, qsum = 0.0f;
        for (int i = t; i < N_; i += 256) {
            float a = (a0[i] + a0[N_ + i] + a0[2 * N_ + i]) * (1.0f / 3.0f);
            out_avg[b * N_ + i] = a;
            esum -= a * logf(a + 1e-8f);
            qsum += a * a;
            ukey[i] = flip_f32(a);
        }
        float es = block_sum256(esum, red, t);
        float qs = block_sum256(qsum, red, t);
        if (t == 0) { out_ent[b] = es; out_eff[b] = 1.0f / qs; }
        __syncthreads();
        int rem;
        const unsigned T = radix_kth(ukey, N_, TOP5_, hist4, sdig, t, &rem);
        float tsum = 0.0f;
        for (int i = t; i < N_; i += 256) {
            const unsigned u = ukey[i];
            if (u > T) tsum += unflip_f32(u);
        }
        float ts = block_sum256(tsum, red, t);
        if (t == 0) out_t5[b] = ts + (float)rem * unflip_f32(T);
    }
}

// ---------------- K7a: x1 = cat @ Wf1 + bf1 (cat folded in; split-K GEMV) ----------
__global__ __launch_bounds__(256)
void k_fuse1(const float* __restrict__ ws_part, const float* __restrict__ ws_stats,
             const float* __restrict__ Wf1, const float* __restrict__ bf1,
             float* __restrict__ x1)
{
    __shared__ float cl[1280];
    __shared__ float part[256];
    const int blk = blockIdx.x;                 // b*8 + c
    const int b = blk >> 3, c = blk & 7;
    const int t = threadIdx.x;
    const float inv0 = 1.0f / fmaxf(ws_stats[b], 1.0f);
    const float inv1 = 1.0f / fmaxf(ws_stats[64 + b], 1.0f);
    for (int i = t; i < 1280; i += 256) {
        const int j = i >> 8, d = i & 255;
        float s = 0.0f;
        #pragma unroll
        for (int cc = 0; cc < 8; ++cc)
            s += ws_part[((size_t)(b * 8 + cc) * 5 + j) * 256 + d];
        if (j == 0)      s *= inv0;
        else if (j == 1) s *= inv1;
        cl[i] = s;
    }
    __syncthreads();
    const int j = c * 64 + (t & 63);
    const int s = t >> 6;
    float acc = 0.0f;
    const float* wp = Wf1 + (size_t)(s * 320) * 512 + j;
    #pragma unroll 8
    for (int i = 0; i < 320; ++i)
        acc = fmaf(cl[s * 320 + i], wp[(size_t)i * 512], acc);
    part[t] = acc;
    __syncthreads();
    if (t < 64)
        x1[b * 512 + c * 64 + t] =
            part[t] + part[64 + t] + part[128 + t] + part[192 + t] + bf1[c * 64 + t];
}

// ---------------- K7b: LN + GELU + bag = g @ Wf2 + bf2 (512 blocks, LN redundant) --
__global__ __launch_bounds__(256)
void k_fuse23(const float* __restrict__ x1, const float* __restrict__ ln_g,
              const float* __restrict__ ln_b, const float* __restrict__ Wf2,
              const float* __restrict__ bf2, float* __restrict__ out_bag)
{
    __shared__ float gl[512];
    __shared__ float part[256];
    __shared__ float red[4];
    const int blk = blockIdx.x;                 // b*8 + c
    const int b = blk >> 3, c = blk & 7;
    const int t = threadIdx.x;
    // LN + GELU (identical arithmetic in all 8 blocks of a batch -> bitwise same)
    float v0 = x1[b * 512 + t], v1 = x1[b * 512 + 256 + t];
    float mu = block_sum256(v0 + v1, red, t) * (1.0f / 512.0f);
    float d0 = v0 - mu, d1 = v1 - mu;
    float var = block_sum256(d0 * d0 + d1 * d1, red, t) * (1.0f / 512.0f);
    float is = 1.0f / sqrtf(var + 1e-5f);
    float y0 = d0 * is * ln_g[t] + ln_b[t];
    float y1 = d1 * is * ln_g[t + 256] + ln_b[t + 256];
    gl[t]       = 0.5f * y0 * (1.0f + erff(y0 * 0.70710678118654752440f));
    gl[t + 256] = 0.5f * y1 * (1.0f + erff(y1 * 0.70710678118654752440f));
    __syncthreads();
    // split-K GEMV: this block covers output cols c*64..c*64+63
    const int j = c * 64 + (t & 63);
    const int s = t >> 6;
    float acc = 0.0f;
    const float* wp = Wf2 + (size_t)(s * 128) * 512 + j;
    #pragma unroll 8
    for (int i = 0; i < 128; ++i)
        acc = fmaf(gl[s * 128 + i], wp[(size_t)i * 512], acc);
    part[t] = acc;
    __syncthreads();
    if (t < 64)
        out_bag[b * 512 + c * 64 + t] =
            part[t] + part[64 + t] + part[128 + t] + part[192 + t] + bf2[c * 64 + t];
}

extern "C" void kernel_launch(void* const* d_in, const int* in_sizes, int n_in,
                              void* d_out, int out_size, void* d_ws, size_t ws_size,
                              hipStream_t stream)
{
    (void)in_sizes; (void)n_in; (void)out_size; (void)ws_size;
    const float* inst = (const float*)d_in[0];
    const float* mask = (const float*)d_in[1];
    const float* Ws1  = (const float*)d_in[2];
    const float* bs1  = (const float*)d_in[3];
    const float* Ws2  = (const float*)d_in[4];
    const float* bs2  = (const float*)d_in[5];
    const float* Wa1  = (const float*)d_in[6];
    const float* ba1  = (const float*)d_in[7];
    const float* Wa2  = (const float*)d_in[8];
    const float* ba2  = (const float*)d_in[9];
    const float* Wf1  = (const float*)d_in[10];
    const float* bf1  = (const float*)d_in[11];
    const float* lng  = (const float*)d_in[12];
    const float* lnb  = (const float*)d_in[13];
    const float* Wf2  = (const float*)d_in[14];
    const float* bf2  = (const float*)d_in[15];

    float* out = (float*)d_out;
    float* ws  = (float*)d_ws;
    short* wsB = (short*)(ws + WS_BFRAG);

    k_prep<<<32, 256, 0, stream>>>(Ws1, Wa1, wsB);
    k_scores<<<M_ / 64, 256, 0, stream>>>(inst, mask, wsB, bs1, Ws2, bs2,
                                          ba1, Wa2, ba2, ws);
    k_sel<<<256, 256, 0, stream>>>(ws + WS_TK, ws + WS_SC, mask,
                                   out + OUT_TOPK, out + OUT_ATTN, ws + WS_STATS);
    k_pd<<<576, 256, 0, stream>>>(inst, mask, out + OUT_TOPK, out + OUT_ATTN,
                                  ws + WS_PART, out + OUT_AVG, out + OUT_ENT,
                                  out + OUT_EFF, out + OUT_T5);
    k_fuse1<<<B_ * 8, 256, 0, stream>>>(ws + WS_PART, ws + WS_STATS, Wf1, bf1,
                                        ws + WS_X1);
    k_fuse23<<<B_ * 8, 256, 0, stream>>>(ws + WS_X1, lng, lnb, Wf2, bf2,
                                         out + OUT_BAG);
}